// Round 1
// 427.743 us; speedup vs baseline: 1.3513x; 1.3513x over previous
//
#include <hip/hip_runtime.h>

// GCN 2-layer + mean-pool + readout.
// Key algebraic move: aggregation is linear, so transform FIRST:
//   Y      = (norm_out ⊙ X) @ W1                       (dense streaming GEMM)
//   h1[n]  = relu( norm_in[n] * sum_{e:dst=n} Y[src_e] + b1 )
//   out    = ((1/N) * sum_u c[u]*h1[u]) @ W2 + b2  @ Wr^T + br
//   c[u]   = norm_out[u] * sum_{e:src=u} norm_in[dst_e]
// The gather kernel then carries NO weight matrix (no LDS cap -> 8 waves/SIMD)
// and does only row-sums (no per-edge weight load / fma chain).
//
// Pipeline: memset -> k_deg -> k_norm(+block partial sums) -> k_scanp ->
//           k_rowptr(row_ptr + cursor init) -> k_scatter -> k_xform ->
//           k_agg -> k_final.

constexpr int NN = 50000;
constexpr int NE = 800000;

// ws layout in 4-byte units:
constexpr int OFF_DEG_OUT  = 0;        // int[50000]   (zeroed)
constexpr int OFF_DEG_IN   = 50000;    // int[50000]   (zeroed)
constexpr int OFF_CRAW     = 100000;   // float[50000] (zeroed)
constexpr int OFF_SVEC     = 150000;   // float[256]   (zeroed)
constexpr int OFF_PART     = 150256;   // int[256]
constexpr int OFF_BOFF     = 150512;   // int[256]
constexpr int OFF_NORM_OUT = 150768;   // float[50000]
constexpr int OFF_NORM_IN  = 200768;   // float[50000]
constexpr int OFF_ROW_PTR  = 250768;   // int[50001]
constexpr int OFF_CURSOR   = 300769;   // int[50000]
constexpr int OFF_EDGE_SRC = 350769;   // int[800000]
constexpr int OFF_Y        = 1150772;  // float[50000*96] (16B aligned)
constexpr size_t ZERO_BYTES = (size_t)(OFF_SVEC + 256) * 4;

__global__ void k_deg(const int* __restrict__ src, const int* __restrict__ dst,
                      int* __restrict__ deg_out, int* __restrict__ deg_in) {
  int e = blockIdx.x * blockDim.x + threadIdx.x;
  if (e < NE) {
    atomicAdd(&deg_out[src[e]], 1);
    atomicAdd(&deg_in[dst[e]], 1);
  }
}

// norms + per-block partial sums of deg_in (phase A of the parallel scan)
__global__ void k_norm(const int* __restrict__ deg_out, const int* __restrict__ deg_in,
                       float* __restrict__ norm_out, float* __restrict__ norm_in,
                       int* __restrict__ partials) {
  __shared__ int sred[256];
  int t = threadIdx.x;
  int n = blockIdx.x * 256 + t;
  int di = (n < NN) ? deg_in[n] : 0;
  if (n < NN) {
    norm_out[n] = 1.0f / sqrtf((float)max(deg_out[n], 1));
    norm_in[n]  = 1.0f / sqrtf((float)di > 0.f ? (float)di : 1.0f);
  }
  sred[t] = di;
  __syncthreads();
  for (int s = 128; s > 0; s >>= 1) {
    if (t < s) sred[t] += sred[t + s];
    __syncthreads();
  }
  if (t == 0) partials[blockIdx.x] = sred[0];
}

// phase B: exclusive scan of the 196 block partials (1 block)
__global__ void k_scanp(const int* __restrict__ partials, int* __restrict__ block_off,
                        int* __restrict__ row_ptr) {
  __shared__ int sc[256];
  int t = threadIdx.x;
  int v = (t < 196) ? partials[t] : 0;
  sc[t] = v;
  __syncthreads();
  for (int off = 1; off < 256; off <<= 1) {
    int u = (t >= off) ? sc[t - off] : 0;
    __syncthreads();
    sc[t] += u;
    __syncthreads();
  }
  block_off[t] = sc[t] - v;          // exclusive prefix
  if (t == 255) row_ptr[NN] = sc[255];
}

// phase C: row_ptr via per-block scan; also init cursor = row_ptr so the
// scatter kernel needs no separate random row_ptr read.
__global__ void k_rowptr(const int* __restrict__ deg_in, const int* __restrict__ block_off,
                         int* __restrict__ row_ptr, int* __restrict__ cursor) {
  __shared__ int sc[256];
  int t = threadIdx.x;
  int idx = blockIdx.x * 256 + t;
  int d = (idx < NN) ? deg_in[idx] : 0;
  sc[t] = d;
  __syncthreads();
  for (int off = 1; off < 256; off <<= 1) {
    int u = (t >= off) ? sc[t - off] : 0;
    __syncthreads();
    sc[t] += u;
    __syncthreads();
  }
  int base = block_off[blockIdx.x] + (sc[t] - d);
  if (idx < NN) { row_ptr[idx] = base; cursor[idx] = base; }
}

// Counting-sort edges by dst (cursor pre-initialized to row base) + c_raw.
__global__ void k_scatter(const int* __restrict__ src, const int* __restrict__ dst,
                          int* __restrict__ cursor, const float* __restrict__ norm_in,
                          int* __restrict__ edge_src, float* __restrict__ c_raw) {
  int e = blockIdx.x * blockDim.x + threadIdx.x;
  if (e < NE) {
    int d = dst[e], s = src[e];
    int pos = atomicAdd(&cursor[d], 1);
    edge_src[pos] = s;
    atomicAdd(&c_raw[s], norm_in[d]);
  }
}

// Y[n] = (norm_out[n] * X[n]) @ W1   — streaming shfl-GEMM, 32 lanes per node.
__global__ __launch_bounds__(256)
void k_xform(const float* __restrict__ feats, const float* __restrict__ norm_out,
             const float* __restrict__ W1, float* __restrict__ Y) {
  __shared__ float W1s[96 * 96];
  int tid = threadIdx.x;
  for (int i = tid; i < 96 * 96 / 4; i += 256)
    ((float4*)W1s)[i] = ((const float4*)W1)[i];
  __syncthreads();

  const int g = tid >> 5, l = tid & 31;
  const int gid = blockIdx.x * 8 + g;
  const int gstride = gridDim.x * 8;

  for (int n = gid; n < NN; n += gstride) {
    const float* r = feats + (size_t)n * 96;
    float no = norm_out[n];
    float x0 = r[l] * no, x1 = r[l + 32] * no, x2 = r[l + 64] * no;
    float h0 = 0.f, h1 = 0.f, h2 = 0.f;
#pragma unroll
    for (int kb = 0; kb < 3; ++kb) {
      float xv = (kb == 0) ? x0 : (kb == 1) ? x1 : x2;
#pragma unroll
      for (int kk = 0; kk < 32; ++kk) {
        int k = kb * 32 + kk;
        float vk = __shfl(xv, kk, 32);
        h0 = fmaf(vk, W1s[k * 96 + l],      h0);
        h1 = fmaf(vk, W1s[k * 96 + l + 32], h1);
        h2 = fmaf(vk, W1s[k * 96 + l + 64], h2);
      }
    }
    float* yr = Y + (size_t)n * 96;
    yr[l] = h0; yr[l + 32] = h1; yr[l + 64] = h2;
  }
}

// CSR gather of Y rows (pure row-sum), relu-epilogue, weighted global sum.
// No weight matrix -> tiny LDS -> 8 waves/SIMD; grid 2048 -> 32 waves/CU.
__global__ __launch_bounds__(256, 8)
void k_agg(const float* __restrict__ Y,
           const float* __restrict__ norm_out, const float* __restrict__ norm_in,
           const float* __restrict__ c_raw,
           const int* __restrict__ row_ptr, const int* __restrict__ edge_src,
           const float* __restrict__ b1, float* __restrict__ svec) {
  __shared__ float red[96];
  int tid = threadIdx.x;
  if (tid < 96) red[tid] = 0.f;
  __syncthreads();

  const int g = tid >> 5, l = tid & 31;
  const float B0 = b1[l], B1 = b1[l + 32], B2 = b1[l + 64];
  float a0 = 0.f, a1 = 0.f, a2 = 0.f;

  const int gid = blockIdx.x * 8 + g;
  const int gstride = gridDim.x * 8;

  for (int n = gid; n < NN; n += gstride) {
    int e0 = row_ptr[n], e1 = row_ptr[n + 1];
    float v0 = 0.f, v1 = 0.f, v2 = 0.f;
    for (int base = e0; base < e1; base += 32) {
      int idx = base + l;
      int es = (idx < e1) ? edge_src[idx] : 0;
      int cnt = min(32, e1 - base);
      int t2 = 0;
      for (; t2 + 3 < cnt; t2 += 4) {      // 4-edge unroll: 12 loads in flight
        int s0 = __shfl(es, t2, 32),     s1 = __shfl(es, t2 + 1, 32);
        int s2 = __shfl(es, t2 + 2, 32), s3 = __shfl(es, t2 + 3, 32);
        const float* r0 = Y + (size_t)s0 * 96;
        const float* r1 = Y + (size_t)s1 * 96;
        const float* r2 = Y + (size_t)s2 * 96;
        const float* r3 = Y + (size_t)s3 * 96;
        float p0 = r0[l], p1 = r0[l + 32], p2 = r0[l + 64];
        float q0 = r1[l], q1 = r1[l + 32], q2 = r1[l + 64];
        float u0 = r2[l], u1 = r2[l + 32], u2 = r2[l + 64];
        float w0 = r3[l], w1 = r3[l + 32], w2 = r3[l + 64];
        v0 += (p0 + q0) + (u0 + w0);
        v1 += (p1 + q1) + (u1 + w1);
        v2 += (p2 + q2) + (u2 + w2);
      }
      for (; t2 < cnt; ++t2) {
        int s0 = __shfl(es, t2, 32);
        const float* r0 = Y + (size_t)s0 * 96;
        v0 += r0[l]; v1 += r0[l + 32]; v2 += r0[l + 64];
      }
    }
    float ni = norm_in[n];
    float cw = norm_out[n] * c_raw[n];
    a0 += cw * fmaxf(fmaf(ni, v0, B0), 0.f);
    a1 += cw * fmaxf(fmaf(ni, v1, B1), 0.f);
    a2 += cw * fmaxf(fmaf(ni, v2, B2), 0.f);
  }

  atomicAdd(&red[l],      a0);
  atomicAdd(&red[l + 32], a1);
  atomicAdd(&red[l + 64], a2);
  __syncthreads();
  if (tid < 96) atomicAdd(&svec[tid], red[tid]);
}

// hg = (svec/N) @ W2 + b2 ; out = hg @ Wr^T + br
__global__ void k_final(const float* __restrict__ svec,
                        const float* __restrict__ W2, const float* __restrict__ b2,
                        const float* __restrict__ Wr, const float* __restrict__ br,
                        float* __restrict__ out) {
  __shared__ float hg[96];
  int j = threadIdx.x;
  if (j < 96) {
    float acc = b2[j];
    const float invN = 1.0f / (float)NN;
    for (int k = 0; k < 96; ++k)
      acc = fmaf(svec[k] * invN, W2[k * 96 + j], acc);
    hg[j] = acc;
  }
  __syncthreads();
  if (j < 8) {
    float acc = br[j];
    for (int k = 0; k < 96; ++k)
      acc = fmaf(hg[k], Wr[j * 96 + k], acc);
    out[j] = acc;
  }
}

extern "C" void kernel_launch(void* const* d_in, const int* in_sizes, int n_in,
                              void* d_out, int out_size, void* d_ws, size_t ws_size,
                              hipStream_t stream) {
  const float* feats = (const float*)d_in[0];
  const int*   src   = (const int*)d_in[1];
  const int*   dst   = (const int*)d_in[2];
  const float* W1    = (const float*)d_in[3];
  const float* b1    = (const float*)d_in[4];
  const float* W2    = (const float*)d_in[5];
  const float* b2    = (const float*)d_in[6];
  const float* Wr    = (const float*)d_in[7];
  const float* br    = (const float*)d_in[8];
  float* out = (float*)d_out;

  int*   wsi      = (int*)d_ws;
  float* wsf      = (float*)d_ws;
  int*   deg_out  = wsi + OFF_DEG_OUT;
  int*   deg_in   = wsi + OFF_DEG_IN;
  float* c_raw    = wsf + OFF_CRAW;
  float* svec     = wsf + OFF_SVEC;
  int*   partials = wsi + OFF_PART;
  int*   block_off= wsi + OFF_BOFF;
  float* norm_out = wsf + OFF_NORM_OUT;
  float* norm_in  = wsf + OFF_NORM_IN;
  int*   row_ptr  = wsi + OFF_ROW_PTR;
  int*   cursor   = wsi + OFF_CURSOR;
  int*   edge_src = wsi + OFF_EDGE_SRC;
  float* Y        = wsf + OFF_Y;

  hipMemsetAsync(d_ws, 0, ZERO_BYTES, stream);

  k_deg<<<(NE + 255) / 256, 256, 0, stream>>>(src, dst, deg_out, deg_in);
  k_norm<<<(NN + 255) / 256, 256, 0, stream>>>(deg_out, deg_in, norm_out, norm_in, partials);
  k_scanp<<<1, 256, 0, stream>>>(partials, block_off, row_ptr);
  k_rowptr<<<(NN + 255) / 256, 256, 0, stream>>>(deg_in, block_off, row_ptr, cursor);
  k_scatter<<<(NE + 255) / 256, 256, 0, stream>>>(src, dst, cursor, norm_in, edge_src, c_raw);
  k_xform<<<1024, 256, 0, stream>>>(feats, norm_out, W1, Y);
  k_agg<<<2048, 256, 0, stream>>>(Y, norm_out, norm_in, c_raw, row_ptr, edge_src, b1, svec);
  k_final<<<1, 128, 0, stream>>>(svec, W2, b2, Wr, br, out);
}

// Round 3
// 365.101 us; speedup vs baseline: 1.5831x; 1.1716x over previous
//
#include <hip/hip_runtime.h>

// GCN 2-layer + mean-pool + readout.
// Algebra: aggregation is linear, so transform FIRST:
//   Y      = (norm_out ⊙ X) @ W1                       (dense register-tiled GEMM)
//   h1[n]  = relu( norm_in[n] * sum_{e:dst=n} Y[src_e] + b1 )
//   out    = ((1/N) * sum_u c[u]*h1[u]) @ W2 + b2  @ Wr^T + br
//   c[u]   = norm_out[u] * sum_{e:src=u} norm_in[dst_e]
//
// Pipeline: memset -> k_deg -> k_norm(+block partial sums) -> k_scanp ->
//           k_rowptr(row_ptr + cursor init) -> k_scatter -> k_xform ->
//           k_agg -> k_final.

constexpr int NN = 50000;
constexpr int NE = 800000;

// ws layout in 4-byte units:
constexpr int OFF_DEG_OUT  = 0;        // int[50000]   (zeroed)
constexpr int OFF_DEG_IN   = 50000;    // int[50000]   (zeroed)
constexpr int OFF_CRAW     = 100000;   // float[50000] (zeroed)
constexpr int OFF_SVEC     = 150000;   // float[256]   (zeroed)
constexpr int OFF_PART     = 150256;   // int[256]
constexpr int OFF_BOFF     = 150512;   // int[256]
constexpr int OFF_NORM_OUT = 150768;   // float[50000]
constexpr int OFF_NORM_IN  = 200768;   // float[50000]
constexpr int OFF_ROW_PTR  = 250768;   // int[50001]
constexpr int OFF_CURSOR   = 300769;   // int[50000]
constexpr int OFF_EDGE_SRC = 350769;   // int[800000]
constexpr int OFF_Y        = 1150772;  // float[50000*96] (16B aligned)
constexpr size_t ZERO_BYTES = (size_t)(OFF_SVEC + 256) * 4;

__global__ void k_deg(const int* __restrict__ src, const int* __restrict__ dst,
                      int* __restrict__ deg_out, int* __restrict__ deg_in) {
  int e = blockIdx.x * blockDim.x + threadIdx.x;
  if (e < NE) {
    atomicAdd(&deg_out[src[e]], 1);
    atomicAdd(&deg_in[dst[e]], 1);
  }
}

// norms + per-block partial sums of deg_in (phase A of the parallel scan)
__global__ void k_norm(const int* __restrict__ deg_out, const int* __restrict__ deg_in,
                       float* __restrict__ norm_out, float* __restrict__ norm_in,
                       int* __restrict__ partials) {
  __shared__ int sred[256];
  int t = threadIdx.x;
  int n = blockIdx.x * 256 + t;
  int di = (n < NN) ? deg_in[n] : 0;
  if (n < NN) {
    norm_out[n] = 1.0f / sqrtf((float)max(deg_out[n], 1));
    norm_in[n]  = 1.0f / sqrtf((float)di > 0.f ? (float)di : 1.0f);
  }
  sred[t] = di;
  __syncthreads();
  for (int s = 128; s > 0; s >>= 1) {
    if (t < s) sred[t] += sred[t + s];
    __syncthreads();
  }
  if (t == 0) partials[blockIdx.x] = sred[0];
}

// phase B: exclusive scan of the 196 block partials (1 block)
__global__ void k_scanp(const int* __restrict__ partials, int* __restrict__ block_off,
                        int* __restrict__ row_ptr) {
  __shared__ int sc[256];
  int t = threadIdx.x;
  int v = (t < 196) ? partials[t] : 0;
  sc[t] = v;
  __syncthreads();
  for (int off = 1; off < 256; off <<= 1) {
    int u = (t >= off) ? sc[t - off] : 0;
    __syncthreads();
    sc[t] += u;
    __syncthreads();
  }
  block_off[t] = sc[t] - v;          // exclusive prefix
  if (t == 255) row_ptr[NN] = sc[255];
}

// phase C: row_ptr via per-block scan; also init cursor = row_ptr so the
// scatter kernel needs no separate random row_ptr read.
__global__ void k_rowptr(const int* __restrict__ deg_in, const int* __restrict__ block_off,
                         int* __restrict__ row_ptr, int* __restrict__ cursor) {
  __shared__ int sc[256];
  int t = threadIdx.x;
  int idx = blockIdx.x * 256 + t;
  int d = (idx < NN) ? deg_in[idx] : 0;
  sc[t] = d;
  __syncthreads();
  for (int off = 1; off < 256; off <<= 1) {
    int u = (t >= off) ? sc[t - off] : 0;
    __syncthreads();
    sc[t] += u;
    __syncthreads();
  }
  int base = block_off[blockIdx.x] + (sc[t] - d);
  if (idx < NN) { row_ptr[idx] = base; cursor[idx] = base; }
}

// Counting-sort edges by dst (cursor pre-initialized to row base) + c_raw.
__global__ void k_scatter(const int* __restrict__ src, const int* __restrict__ dst,
                          int* __restrict__ cursor, const float* __restrict__ norm_in,
                          int* __restrict__ edge_src, float* __restrict__ c_raw) {
  int e = blockIdx.x * blockDim.x + threadIdx.x;
  if (e < NE) {
    int d = dst[e], s = src[e];
    int pos = atomicAdd(&cursor[d], 1);
    edge_src[pos] = s;
    atomicAdd(&c_raw[s], norm_in[d]);
  }
}

// Y = (norm_out ⊙ X) @ W1 — register-tiled GEMM.
// One 64-node tile per block. X-tile staged TRANSPOSED in LDS (26 KB, no W1
// in LDS -> 6 blocks/CU). Thread (tn=t&7, tm=t>>3) computes 2 nodes x 12 cols.
// Per k: 1 ds_read_b64 (x pair, broadcast) + 3 dwordx4 W1 (L1-resident) + 24 fma.
__global__ __launch_bounds__(256, 6)
void k_xform(const float* __restrict__ feats, const float* __restrict__ norm_out,
             const float* __restrict__ W1, float* __restrict__ Y) {
  __shared__ float XT[96][68];            // [k][node], pad 64->68 (16B-aligned rows)
  const int t = threadIdx.x;
  const int nb = blockIdx.x * 64;         // tile base node

  // ---- stage: coalesced float4 global reads -> transposed LDS writes ----
  const float4* f4 = (const float4*)feats;
#pragma unroll
  for (int i = 0; i < 6; ++i) {           // 6*256 = 1536 float4 = 64x96 floats
    int idx4 = i * 256 + t;
    int n = idx4 / 24;                    // node within tile (24 float4 per row)
    int kq = idx4 % 24;
    int ng = nb + n;
    float4 v = make_float4(0.f, 0.f, 0.f, 0.f);
    float no = 0.f;
    if (ng < NN) { v = f4[(size_t)ng * 24 + kq]; no = norm_out[ng]; }
    XT[kq * 4 + 0][n] = v.x * no;
    XT[kq * 4 + 1][n] = v.y * no;
    XT[kq * 4 + 2][n] = v.z * no;
    XT[kq * 4 + 3][n] = v.w * no;
  }
  __syncthreads();

  // ---- compute: 2 nodes x 12 cols per thread ----
  const int tn = t & 7;                   // column chunk: cols 12*tn .. 12*tn+11
  const int tm = t >> 3;                  // node pair: nodes 2*tm, 2*tm+1
  float acc0[12], acc1[12];
#pragma unroll
  for (int c = 0; c < 12; ++c) { acc0[c] = 0.f; acc1[c] = 0.f; }

  const float4* W4 = (const float4*)(W1 + 12 * tn);   // row stride 24 float4
#pragma unroll 4
  for (int k = 0; k < 96; ++k) {
    float2 x = *(const float2*)&XT[k][2 * tm];
    float4 w0 = W4[k * 24 + 0];
    float4 w1 = W4[k * 24 + 1];
    float4 w2 = W4[k * 24 + 2];
    const float w[12] = {w0.x, w0.y, w0.z, w0.w, w1.x, w1.y, w1.z, w1.w,
                         w2.x, w2.y, w2.z, w2.w};
#pragma unroll
    for (int c = 0; c < 12; ++c) {
      acc0[c] = fmaf(x.x, w[c], acc0[c]);
      acc1[c] = fmaf(x.y, w[c], acc1[c]);
    }
  }

  // ---- store: 3 float4 per node, coalesced across tn ----
  int n0 = nb + 2 * tm;
  if (n0 < NN) {
    float4* y4 = (float4*)(Y + (size_t)n0 * 96 + 12 * tn);
    y4[0] = make_float4(acc0[0], acc0[1], acc0[2], acc0[3]);
    y4[1] = make_float4(acc0[4], acc0[5], acc0[6], acc0[7]);
    y4[2] = make_float4(acc0[8], acc0[9], acc0[10], acc0[11]);
  }
  if (n0 + 1 < NN) {
    float4* y4 = (float4*)(Y + (size_t)(n0 + 1) * 96 + 12 * tn);
    y4[0] = make_float4(acc1[0], acc1[1], acc1[2], acc1[3]);
    y4[1] = make_float4(acc1[4], acc1[5], acc1[6], acc1[7]);
    y4[2] = make_float4(acc1[8], acc1[9], acc1[10], acc1[11]);
  }
}

// CSR gather of Y rows (pure row-sum), relu-epilogue, weighted global sum.
__global__ __launch_bounds__(256, 8)
void k_agg(const float* __restrict__ Y,
           const float* __restrict__ norm_out, const float* __restrict__ norm_in,
           const float* __restrict__ c_raw,
           const int* __restrict__ row_ptr, const int* __restrict__ edge_src,
           const float* __restrict__ b1, float* __restrict__ svec) {
  __shared__ float red[96];
  int tid = threadIdx.x;
  if (tid < 96) red[tid] = 0.f;
  __syncthreads();

  const int g = tid >> 5, l = tid & 31;
  const float B0 = b1[l], B1 = b1[l + 32], B2 = b1[l + 64];
  float a0 = 0.f, a1 = 0.f, a2 = 0.f;

  const int gid = blockIdx.x * 8 + g;
  const int gstride = gridDim.x * 8;

  for (int n = gid; n < NN; n += gstride) {
    int e0 = row_ptr[n], e1 = row_ptr[n + 1];
    float v0 = 0.f, v1 = 0.f, v2 = 0.f;
    for (int base = e0; base < e1; base += 32) {
      int idx = base + l;
      int es = (idx < e1) ? edge_src[idx] : 0;
      int cnt = min(32, e1 - base);
      int t2 = 0;
      for (; t2 + 3 < cnt; t2 += 4) {      // 4-edge unroll: 12 loads in flight
        int s0 = __shfl(es, t2, 32),     s1 = __shfl(es, t2 + 1, 32);
        int s2 = __shfl(es, t2 + 2, 32), s3 = __shfl(es, t2 + 3, 32);
        const float* r0 = Y + (size_t)s0 * 96;
        const float* r1 = Y + (size_t)s1 * 96;
        const float* r2 = Y + (size_t)s2 * 96;
        const float* r3 = Y + (size_t)s3 * 96;
        float p0 = r0[l], p1 = r0[l + 32], p2 = r0[l + 64];
        float q0 = r1[l], q1 = r1[l + 32], q2 = r1[l + 64];
        float u0 = r2[l], u1 = r2[l + 32], u2 = r2[l + 64];
        float w0 = r3[l], w1 = r3[l + 32], w2 = r3[l + 64];
        v0 += (p0 + q0) + (u0 + w0);
        v1 += (p1 + q1) + (u1 + w1);
        v2 += (p2 + q2) + (u2 + w2);
      }
      for (; t2 < cnt; ++t2) {
        int s0 = __shfl(es, t2, 32);
        const float* r0 = Y + (size_t)s0 * 96;
        v0 += r0[l]; v1 += r0[l + 32]; v2 += r0[l + 64];
      }
    }
    float ni = norm_in[n];
    float cw = norm_out[n] * c_raw[n];
    a0 += cw * fmaxf(fmaf(ni, v0, B0), 0.f);
    a1 += cw * fmaxf(fmaf(ni, v1, B1), 0.f);
    a2 += cw * fmaxf(fmaf(ni, v2, B2), 0.f);
  }

  atomicAdd(&red[l],      a0);
  atomicAdd(&red[l + 32], a1);
  atomicAdd(&red[l + 64], a2);
  __syncthreads();
  if (tid < 96) atomicAdd(&svec[tid], red[tid]);
}

// hg = (svec/N) @ W2 + b2 ; out = hg @ Wr^T + br
__global__ void k_final(const float* __restrict__ svec,
                        const float* __restrict__ W2, const float* __restrict__ b2,
                        const float* __restrict__ Wr, const float* __restrict__ br,
                        float* __restrict__ out) {
  __shared__ float hg[96];
  int j = threadIdx.x;
  if (j < 96) {
    float acc = b2[j];
    const float invN = 1.0f / (float)NN;
    for (int k = 0; k < 96; ++k)
      acc = fmaf(svec[k] * invN, W2[k * 96 + j], acc);
    hg[j] = acc;
  }
  __syncthreads();
  if (j < 8) {
    float acc = br[j];
    for (int k = 0; k < 96; ++k)
      acc = fmaf(hg[k], Wr[j * 96 + k], acc);
    out[j] = acc;
  }
}

extern "C" void kernel_launch(void* const* d_in, const int* in_sizes, int n_in,
                              void* d_out, int out_size, void* d_ws, size_t ws_size,
                              hipStream_t stream) {
  const float* feats = (const float*)d_in[0];
  const int*   src   = (const int*)d_in[1];
  const int*   dst   = (const int*)d_in[2];
  const float* W1    = (const float*)d_in[3];
  const float* b1    = (const float*)d_in[4];
  const float* W2    = (const float*)d_in[5];
  const float* b2    = (const float*)d_in[6];
  const float* Wr    = (const float*)d_in[7];
  const float* br    = (const float*)d_in[8];
  float* out = (float*)d_out;

  int*   wsi      = (int*)d_ws;
  float* wsf      = (float*)d_ws;
  int*   deg_out  = wsi + OFF_DEG_OUT;
  int*   deg_in   = wsi + OFF_DEG_IN;
  float* c_raw    = wsf + OFF_CRAW;
  float* svec     = wsf + OFF_SVEC;
  int*   partials = wsi + OFF_PART;
  int*   block_off= wsi + OFF_BOFF;
  float* norm_out = wsf + OFF_NORM_OUT;
  float* norm_in  = wsf + OFF_NORM_IN;
  int*   row_ptr  = wsi + OFF_ROW_PTR;
  int*   cursor   = wsi + OFF_CURSOR;
  int*   edge_src = wsi + OFF_EDGE_SRC;
  float* Y        = wsf + OFF_Y;

  hipMemsetAsync(d_ws, 0, ZERO_BYTES, stream);

  k_deg<<<(NE + 255) / 256, 256, 0, stream>>>(src, dst, deg_out, deg_in);
  k_norm<<<(NN + 255) / 256, 256, 0, stream>>>(deg_out, deg_in, norm_out, norm_in, partials);
  k_scanp<<<1, 256, 0, stream>>>(partials, block_off, row_ptr);
  k_rowptr<<<(NN + 255) / 256, 256, 0, stream>>>(deg_in, block_off, row_ptr, cursor);
  k_scatter<<<(NE + 255) / 256, 256, 0, stream>>>(src, dst, cursor, norm_in, edge_src, c_raw);
  k_xform<<<(NN + 63) / 64, 256, 0, stream>>>(feats, norm_out, W1, Y);
  k_agg<<<2048, 256, 0, stream>>>(Y, norm_out, norm_in, c_raw, row_ptr, edge_src, b1, svec);
  k_final<<<1, 128, 0, stream>>>(svec, W2, b2, Wr, br, out);
}

// Round 5
// 307.039 us; speedup vs baseline: 1.8825x; 1.1891x over previous
//
#include <hip/hip_runtime.h>

// GCN 2-layer + mean-pool + readout.
// Algebra: aggregation is linear, so transform FIRST:
//   Y      = (norm_out ⊙ X) @ W1            (dense register-tiled GEMM, fp32)
//   h1[n]  = relu( norm_in[n] * sum_{e:dst=n} Y[src_e] + b1 )
//   out    = ((1/N) * sum_u c[u]*h1[u]) @ W2 + b2  @ Wr^T + br
//   c[u]   = norm_out[u] * sum_{e:src=u} norm_in[dst_e]
//
// k_agg is bound by L2-miss traffic on random gathers of the 19.2 MB Y table
// (no single 4 MB XCD-L2 can hold it). Fix: Y stored as 8 COLUMN PANELS of
// 12 cols (2.4 MB each, contiguous). blockIdx%8 -> XCD (round-robin dispatch),
// so XCD p's blocks sweep ALL nodes but only panel p: the panel stays
// L2-resident in that XCD and gathers become L2 hits. fp32 throughout.
//
// Pipeline: memset -> k_deg(+rank) -> k_norm(+partials) -> k_scanp ->
//           k_rowptr -> k_scatter(rank-placed, no cursor atomic) ->
//           k_xform(panel out) -> k_agg(panel-per-XCD) -> k_final.

constexpr int NN = 50000;
constexpr int NE = 800000;

// ws layout in 4-byte units:
constexpr int OFF_DEG_OUT  = 0;        // int[50000]   (zeroed)
constexpr int OFF_DEG_IN   = 50000;    // int[50000]   (zeroed)
constexpr int OFF_CRAW     = 100000;   // float[50000] (zeroed)
constexpr int OFF_SVEC     = 150000;   // float[256]   (zeroed)
constexpr int OFF_PART     = 150256;   // int[256]
constexpr int OFF_BOFF     = 150512;   // int[256]
constexpr int OFF_NORM_OUT = 150768;   // float[50000]
constexpr int OFF_NORM_IN  = 200768;   // float[50000]
constexpr int OFF_ROW_PTR  = 250768;   // int[50001] -> pad to 300772
constexpr int OFF_EDGE_SRC = 300772;   // int[800000]
constexpr int OFF_RANK     = 1100772;  // int[800000]  (dead after k_scatter)
constexpr int OFF_YP       = 1100772;  // float[8][50000][12] ALIASES rank (safe:
                                       // rank consumed by k_scatter before k_xform)
constexpr size_t ZERO_BYTES = (size_t)(OFF_SVEC + 256) * 4;

__global__ void k_deg(const int* __restrict__ src, const int* __restrict__ dst,
                      int* __restrict__ deg_out, int* __restrict__ deg_in,
                      int* __restrict__ rank) {
  int e = blockIdx.x * blockDim.x + threadIdx.x;
  if (e < NE) {
    atomicAdd(&deg_out[src[e]], 1);
    rank[e] = atomicAdd(&deg_in[dst[e]], 1);   // within-dst-row rank, free
  }
}

// norms + per-block partial sums of deg_in (phase A of the parallel scan)
__global__ void k_norm(const int* __restrict__ deg_out, const int* __restrict__ deg_in,
                       float* __restrict__ norm_out, float* __restrict__ norm_in,
                       int* __restrict__ partials) {
  __shared__ int sred[256];
  int t = threadIdx.x;
  int n = blockIdx.x * 256 + t;
  int di = (n < NN) ? deg_in[n] : 0;
  if (n < NN) {
    norm_out[n] = 1.0f / sqrtf((float)max(deg_out[n], 1));
    norm_in[n]  = 1.0f / sqrtf((float)max(di, 1));
  }
  sred[t] = di;
  __syncthreads();
  for (int s = 128; s > 0; s >>= 1) {
    if (t < s) sred[t] += sred[t + s];
    __syncthreads();
  }
  if (t == 0) partials[blockIdx.x] = sred[0];
}

// phase B: exclusive scan of the 196 block partials (1 block)
__global__ void k_scanp(const int* __restrict__ partials, int* __restrict__ block_off,
                        int* __restrict__ row_ptr) {
  __shared__ int sc[256];
  int t = threadIdx.x;
  int v = (t < 196) ? partials[t] : 0;
  sc[t] = v;
  __syncthreads();
  for (int off = 1; off < 256; off <<= 1) {
    int u = (t >= off) ? sc[t - off] : 0;
    __syncthreads();
    sc[t] += u;
    __syncthreads();
  }
  block_off[t] = sc[t] - v;          // exclusive prefix
  if (t == 255) row_ptr[NN] = sc[255];
}

// phase C: row_ptr via per-block scan.
__global__ void k_rowptr(const int* __restrict__ deg_in, const int* __restrict__ block_off,
                         int* __restrict__ row_ptr) {
  __shared__ int sc[256];
  int t = threadIdx.x;
  int idx = blockIdx.x * 256 + t;
  int d = (idx < NN) ? deg_in[idx] : 0;
  sc[t] = d;
  __syncthreads();
  for (int off = 1; off < 256; off <<= 1) {
    int u = (t >= off) ? sc[t - off] : 0;
    __syncthreads();
    sc[t] += u;
    __syncthreads();
  }
  int base = block_off[blockIdx.x] + (sc[t] - d);
  if (idx < NN) row_ptr[idx] = base;
}

// Place edges by precomputed rank (no cursor atomic) + c_raw accumulation.
__global__ void k_scatter(const int* __restrict__ src, const int* __restrict__ dst,
                          const int* __restrict__ rank, const int* __restrict__ row_ptr,
                          const float* __restrict__ norm_in,
                          int* __restrict__ edge_src, float* __restrict__ c_raw) {
  int e = blockIdx.x * blockDim.x + threadIdx.x;
  if (e < NE) {
    int d = dst[e], s = src[e];
    edge_src[row_ptr[d] + rank[e]] = s;
    atomicAdd(&c_raw[s], norm_in[d]);
  }
}

// Y = (norm_out ⊙ X) @ W1 — register-tiled GEMM, panel-layout fp32 output.
// One 64-node tile per block. X-tile staged TRANSPOSED in LDS (26 KB).
// Thread (tn=t&7, tm=t>>3) computes 2 nodes x 12 cols; tn IS the panel.
__global__ __launch_bounds__(256, 6)
void k_xform(const float* __restrict__ feats, const float* __restrict__ norm_out,
             const float* __restrict__ W1, float* __restrict__ YP) {
  __shared__ float XT[96][68];            // [k][node], pad 64->68
  const int t = threadIdx.x;
  const int nb = blockIdx.x * 64;         // tile base node

  // ---- stage: coalesced float4 global reads -> transposed LDS writes ----
  const float4* f4 = (const float4*)feats;
#pragma unroll
  for (int i = 0; i < 6; ++i) {           // 6*256 = 1536 float4 = 64x96 floats
    int idx4 = i * 256 + t;
    int n = idx4 / 24;                    // node within tile (24 float4 per row)
    int kq = idx4 % 24;
    int ng = nb + n;
    float4 v = make_float4(0.f, 0.f, 0.f, 0.f);
    float no = 0.f;
    if (ng < NN) { v = f4[(size_t)ng * 24 + kq]; no = norm_out[ng]; }
    XT[kq * 4 + 0][n] = v.x * no;
    XT[kq * 4 + 1][n] = v.y * no;
    XT[kq * 4 + 2][n] = v.z * no;
    XT[kq * 4 + 3][n] = v.w * no;
  }
  __syncthreads();

  // ---- compute: 2 nodes x 12 cols per thread ----
  const int tn = t & 7;                   // panel / column chunk: cols 12*tn..
  const int tm = t >> 3;                  // node pair: nodes 2*tm, 2*tm+1
  float acc0[12], acc1[12];
#pragma unroll
  for (int c = 0; c < 12; ++c) { acc0[c] = 0.f; acc1[c] = 0.f; }

  const float4* W4 = (const float4*)(W1 + 12 * tn);   // row stride 24 float4
#pragma unroll 4
  for (int k = 0; k < 96; ++k) {
    float2 x = *(const float2*)&XT[k][2 * tm];
    float4 w0 = W4[k * 24 + 0];
    float4 w1 = W4[k * 24 + 1];
    float4 w2 = W4[k * 24 + 2];
    const float w[12] = {w0.x, w0.y, w0.z, w0.w, w1.x, w1.y, w1.z, w1.w,
                         w2.x, w2.y, w2.z, w2.w};
#pragma unroll
    for (int c = 0; c < 12; ++c) {
      acc0[c] = fmaf(x.x, w[c], acc0[c]);
      acc1[c] = fmaf(x.y, w[c], acc1[c]);
    }
  }

  // ---- store into panel tn: 12 contiguous floats per node ----
  int n0 = nb + 2 * tm;
  if (n0 < NN) {
    float4* yp = (float4*)(YP + ((size_t)tn * NN + n0) * 12);
    yp[0] = make_float4(acc0[0], acc0[1], acc0[2], acc0[3]);
    yp[1] = make_float4(acc0[4], acc0[5], acc0[6], acc0[7]);
    yp[2] = make_float4(acc0[8], acc0[9], acc0[10], acc0[11]);
  }
  if (n0 + 1 < NN) {
    float4* yp = (float4*)(YP + ((size_t)tn * NN + n0 + 1) * 12);
    yp[0] = make_float4(acc1[0], acc1[1], acc1[2], acc1[3]);
    yp[1] = make_float4(acc1[4], acc1[5], acc1[6], acc1[7]);
    yp[2] = make_float4(acc1[8], acc1[9], acc1[10], acc1[11]);
  }
}

// Panel-per-XCD CSR gather. Block b works on panel p = b%8 (lands on XCD p by
// round-robin dispatch), sweeping ALL nodes but only cols [12p,12p+12).
// Panel = 2.4 MB -> L2-resident in its XCD; gathers become L2 hits.
// Lane layout: l<24 active, edge-slot ei=l/3 (8 edges/step), quad q=l%3
// (cols 4q..4q+3 via one float4). Cross-slot reduce: shfl +12,+6,+3.
__global__ __launch_bounds__(256, 8)
void k_agg(const float* __restrict__ YP,
           const float* __restrict__ norm_out, const float* __restrict__ norm_in,
           const float* __restrict__ c_raw,
           const int* __restrict__ row_ptr, const int* __restrict__ edge_src,
           const float* __restrict__ b1, float* __restrict__ svec) {
  __shared__ float red[12];
  const int tid = threadIdx.x;
  if (tid < 12) red[tid] = 0.f;
  __syncthreads();

  const int panel = blockIdx.x & 7;
  const int bp    = blockIdx.x >> 3;        // block index within panel (0..255)
  const int g = tid >> 5, l = tid & 31;
  const int ei = l / 3;                     // edge slot 0..7 (l<24)
  const int q  = l - 3 * ei;                // float4 index within 12-col row
  const bool act = (l < 24);

  const float* Yp = YP + (size_t)panel * NN * 12;
  float4 b4 = make_float4(0.f, 0.f, 0.f, 0.f);
  if (l < 3) b4 = ((const float4*)b1)[3 * panel + l];  // cols 12p+4l..+3

  float a0 = 0.f, a1 = 0.f, a2 = 0.f, a3 = 0.f;        // svec partials (l<3)

  const int gid = bp * 8 + g;               // 0..2047
  for (int n = gid; n < NN; n += 2048) {
    int e0 = row_ptr[n], e1 = row_ptr[n + 1];
    float v0 = 0.f, v1 = 0.f, v2 = 0.f, v3 = 0.f;
    for (int base = e0; base < e1; base += 32) {
      int idx = base + l;
      int es = (idx < e1) ? edge_src[idx] : 0;
      int cnt = min(32, e1 - base);
      // 4 sub-steps of 8 edges; all loads independent (ILP)
      int s0 = __shfl(es, ei, 32);
      int s1 = __shfl(es, 8 + ei, 32);
      int s2 = __shfl(es, 16 + ei, 32);
      int s3 = __shfl(es, 24 + ei, 32);
      float4 f0 = make_float4(0.f, 0.f, 0.f, 0.f), f1 = f0, f2 = f0, f3 = f0;
      if (act && ei < cnt)      f0 = *(const float4*)(Yp + (size_t)s0 * 12 + 4 * q);
      if (act && 8 + ei < cnt)  f1 = *(const float4*)(Yp + (size_t)s1 * 12 + 4 * q);
      if (act && 16 + ei < cnt) f2 = *(const float4*)(Yp + (size_t)s2 * 12 + 4 * q);
      if (act && 24 + ei < cnt) f3 = *(const float4*)(Yp + (size_t)s3 * 12 + 4 * q);
      v0 += (f0.x + f1.x) + (f2.x + f3.x);
      v1 += (f0.y + f1.y) + (f2.y + f3.y);
      v2 += (f0.z + f1.z) + (f2.z + f3.z);
      v3 += (f0.w + f1.w) + (f2.w + f3.w);
    }
    // reduce across the 8 edge slots: lanes 3k+q sum into k=0 (lanes 0..2).
    v0 += __shfl(v0, l + 12, 32); v1 += __shfl(v1, l + 12, 32);
    v2 += __shfl(v2, l + 12, 32); v3 += __shfl(v3, l + 12, 32);
    v0 += __shfl(v0, l + 6, 32);  v1 += __shfl(v1, l + 6, 32);
    v2 += __shfl(v2, l + 6, 32);  v3 += __shfl(v3, l + 6, 32);
    v0 += __shfl(v0, l + 3, 32);  v1 += __shfl(v1, l + 3, 32);
    v2 += __shfl(v2, l + 3, 32);  v3 += __shfl(v3, l + 3, 32);

    if (l < 3) {
      float ni = norm_in[n];
      float cw = norm_out[n] * c_raw[n];
      a0 += cw * fmaxf(fmaf(ni, v0, b4.x), 0.f);
      a1 += cw * fmaxf(fmaf(ni, v1, b4.y), 0.f);
      a2 += cw * fmaxf(fmaf(ni, v2, b4.z), 0.f);
      a3 += cw * fmaxf(fmaf(ni, v3, b4.w), 0.f);
    }
  }

  if (l < 3) {
    atomicAdd(&red[4 * l + 0], a0);
    atomicAdd(&red[4 * l + 1], a1);
    atomicAdd(&red[4 * l + 2], a2);
    atomicAdd(&red[4 * l + 3], a3);
  }
  __syncthreads();
  if (tid < 12) atomicAdd(&svec[12 * panel + tid], red[tid]);
}

// hg = (svec/N) @ W2 + b2 ; out = hg @ Wr^T + br
__global__ void k_final(const float* __restrict__ svec,
                        const float* __restrict__ W2, const float* __restrict__ b2,
                        const float* __restrict__ Wr, const float* __restrict__ br,
                        float* __restrict__ out) {
  __shared__ float hg[96];
  int j = threadIdx.x;
  if (j < 96) {
    float acc = b2[j];
    const float invN = 1.0f / (float)NN;
    for (int k = 0; k < 96; ++k)
      acc = fmaf(svec[k] * invN, W2[k * 96 + j], acc);
    hg[j] = acc;
  }
  __syncthreads();
  if (j < 8) {
    float acc = br[j];
    for (int k = 0; k < 96; ++k)
      acc = fmaf(hg[k], Wr[j * 96 + k], acc);
    out[j] = acc;
  }
}

extern "C" void kernel_launch(void* const* d_in, const int* in_sizes, int n_in,
                              void* d_out, int out_size, void* d_ws, size_t ws_size,
                              hipStream_t stream) {
  const float* feats = (const float*)d_in[0];
  const int*   src   = (const int*)d_in[1];
  const int*   dst   = (const int*)d_in[2];
  const float* W1    = (const float*)d_in[3];
  const float* b1    = (const float*)d_in[4];
  const float* W2    = (const float*)d_in[5];
  const float* b2    = (const float*)d_in[6];
  const float* Wr    = (const float*)d_in[7];
  const float* br    = (const float*)d_in[8];
  float* out = (float*)d_out;

  int*   wsi      = (int*)d_ws;
  float* wsf      = (float*)d_ws;
  int*   deg_out  = wsi + OFF_DEG_OUT;
  int*   deg_in   = wsi + OFF_DEG_IN;
  float* c_raw    = wsf + OFF_CRAW;
  float* svec     = wsf + OFF_SVEC;
  int*   partials = wsi + OFF_PART;
  int*   block_off= wsi + OFF_BOFF;
  float* norm_out = wsf + OFF_NORM_OUT;
  float* norm_in  = wsf + OFF_NORM_IN;
  int*   row_ptr  = wsi + OFF_ROW_PTR;
  int*   edge_src = wsi + OFF_EDGE_SRC;
  int*   rank     = wsi + OFF_RANK;
  float* YP       = wsf + OFF_YP;        // aliases rank (rank dead by then)

  hipMemsetAsync(d_ws, 0, ZERO_BYTES, stream);

  k_deg<<<(NE + 255) / 256, 256, 0, stream>>>(src, dst, deg_out, deg_in, rank);
  k_norm<<<(NN + 255) / 256, 256, 0, stream>>>(deg_out, deg_in, norm_out, norm_in, partials);
  k_scanp<<<1, 256, 0, stream>>>(partials, block_off, row_ptr);
  k_rowptr<<<(NN + 255) / 256, 256, 0, stream>>>(deg_in, block_off, row_ptr);
  k_scatter<<<(NE + 255) / 256, 256, 0, stream>>>(src, dst, rank, row_ptr,
                                                  norm_in, edge_src, c_raw);
  k_xform<<<(NN + 63) / 64, 256, 0, stream>>>(feats, norm_out, W1, YP);
  k_agg<<<2048, 256, 0, stream>>>(YP, norm_out, norm_in, c_raw, row_ptr, edge_src, b1, svec);
  k_final<<<1, 128, 0, stream>>>(svec, W2, b2, Wr, br, out);
}